// Round 1
// baseline (89.936 us; speedup 1.0000x reference)
//
#include <hip/hip_runtime.h>
#include <math.h>

#define LL 4096
#define CC 128
#define SS 64
#define NCH 64
#define CLEN 64   // LL/NCH
#define CS 8192   // CC*SS

// ---------------- kernel 1: projections (B, Cm, dt) ----------------
// grid 256 blocks x 256 thr; each block: 16 rows of x, all 256 output cols.
__global__ __launch_bounds__(256) void k_proj(
    const float* __restrict__ x,
    const float* __restrict__ Bk, const float* __restrict__ Bb,
    const float* __restrict__ Ck, const float* __restrict__ Cb,
    const float* __restrict__ Dk, const float* __restrict__ Db,
    float* __restrict__ Bmat, float* __restrict__ Cmat, float* __restrict__ DTm)
{
    __shared__ float xs[CC][17];   // transposed x tile [k][row], padded
    const int r0 = blockIdx.x * 16;
    const int t = threadIdx.x;
    for (int i = t; i < 16 * CC; i += 256) {
        int r = i >> 7, k = i & 127;
        xs[k][r] = x[(r0 + r) * CC + k];
    }
    __syncthreads();
    const int col = t;             // 0..63 -> B, 64..127 -> Cm, 128..255 -> dt
    const float* W; int stride; float bias;
    if (col < 64)       { W = Bk + col;       stride = SS; bias = 1.0f + Bb[col]; }
    else if (col < 128) { W = Ck + (col-64);  stride = SS; bias = Cb[col-64]; }
    else                { W = Dk + (col-128); stride = CC; bias = Db[col-128] + 0.000244140625f; }
    float acc[16];
#pragma unroll
    for (int r = 0; r < 16; ++r) acc[r] = 0.0f;
    for (int k = 0; k < CC; ++k) {
        float w = W[k * stride];
#pragma unroll
        for (int r = 0; r < 16; ++r) acc[r] = fmaf(w, xs[k][r], acc[r]);
    }
    if (col < 64) {
#pragma unroll
        for (int r = 0; r < 16; ++r) Bmat[(r0 + r) * SS + col] = bias + acc[r];
    } else if (col < 128) {
#pragma unroll
        for (int r = 0; r < 16; ++r) Cmat[(r0 + r) * SS + (col - 64)] = bias + acc[r];
    } else {
#pragma unroll
        for (int r = 0; r < 16; ++r) {
            float z = bias + acc[r];
            float sp = fmaxf(z, 0.0f) + log1pf(__expf(-fabsf(z)));  // stable softplus
            DTm[(r0 + r) * CC + (col - 128)] = sp;
        }
    }
}

// ---------------- kernel 2: per-chunk scan aggregates ----------------
// thread = (chunk, c, s); composes 64 steps into (prod a, acc u)
__global__ __launch_bounds__(256) void k_chunk(
    const float* __restrict__ x, const float* __restrict__ A_log,
    const float* __restrict__ Bmat, const float* __restrict__ DTm,
    float* __restrict__ Aagg, float* __restrict__ Uagg)
{
    const int tid = blockIdx.x * 256 + threadIdx.x;
    const int s = tid & 63;
    const int c = (tid >> 6) & 127;
    const int ch = tid >> 13;
    const float A = -__expf(A_log[c * SS + s]);
    const float invA = 1.0f / A;
    float ap = 1.0f, uc = 0.0f;
    const int l0 = ch * CLEN;
    for (int i = 0; i < CLEN; ++i) {
        const int l = l0 + i;
        const float dtl = DTm[l * CC + c];
        const float xl  = x[l * CC + c];
        const float Bl  = Bmat[l * SS + s];
        const float At  = __expf(A * dtl);
        const float u   = (At - 1.0f) * invA * Bl * xl;
        ap *= At;
        uc = fmaf(At, uc, u);
    }
    Aagg[ch * CS + c * SS + s] = ap;
    Uagg[ch * CS + c * SS + s] = uc;
}

// ---------------- kernel 3: cross-chunk exclusive scan ----------------
__global__ __launch_bounds__(256) void k_scan(
    const float* __restrict__ Aagg, const float* __restrict__ Uagg,
    float* __restrict__ Hpre)
{
    const int j = blockIdx.x * 256 + threadIdx.x;   // (c,s) flat
    float h = 0.0f;
    for (int ch = 0; ch < NCH; ++ch) {
        Hpre[ch * CS + j] = h;
        h = fmaf(Aagg[ch * CS + j], h, Uagg[ch * CS + j]);
    }
}

// ---------------- kernel 4: re-walk + emit y ----------------
// wave = (chunk, c), lanes = s; per step wave-reduce Cm*h
__global__ __launch_bounds__(256) void k_emit(
    const float* __restrict__ x, const float* __restrict__ A_log,
    const float* __restrict__ Bmat, const float* __restrict__ Cmat,
    const float* __restrict__ DTm, const float* __restrict__ Hpre,
    float* __restrict__ y)
{
    const int tid = blockIdx.x * 256 + threadIdx.x;
    const int s = tid & 63;
    const int c = (tid >> 6) & 127;
    const int ch = tid >> 13;
    const float A = -__expf(A_log[c * SS + s]);
    const float invA = 1.0f / A;
    float h = Hpre[ch * CS + c * SS + s];
    const int l0 = ch * CLEN;
    for (int i = 0; i < CLEN; ++i) {
        const int l = l0 + i;
        const float dtl = DTm[l * CC + c];
        const float xl  = x[l * CC + c];
        const float Bl  = Bmat[l * SS + s];
        const float Cl  = Cmat[l * SS + s];
        const float At  = __expf(A * dtl);
        const float u   = (At - 1.0f) * invA * Bl * xl;
        h = fmaf(At, h, u);
        float p = Cl * h;
#pragma unroll
        for (int o = 32; o > 0; o >>= 1) p += __shfl_xor(p, o, 64);
        if (s == 0) y[l * CC + c] = p;
    }
}

extern "C" void kernel_launch(void* const* d_in, const int* in_sizes, int n_in,
                              void* d_out, int out_size, void* d_ws, size_t ws_size,
                              hipStream_t stream)
{
    const float* x  = (const float*)d_in[0];
    const float* Al = (const float*)d_in[1];
    const float* Bk = (const float*)d_in[2];
    const float* Bb = (const float*)d_in[3];
    const float* Ck = (const float*)d_in[4];
    const float* Cb = (const float*)d_in[5];
    const float* Dk = (const float*)d_in[6];
    const float* Db = (const float*)d_in[7];
    float* y  = (float*)d_out;
    float* ws = (float*)d_ws;

    float* Bmat = ws;                    // [L][S]
    float* Cmat = Bmat + LL * SS;        // [L][S]
    float* DTm  = Cmat + LL * SS;        // [L][C]
    float* Aagg = DTm  + LL * CC;        // [NCH][C*S]
    float* Uagg = Aagg + NCH * CS;       // [NCH][C*S]
    float* Hpre = Uagg + NCH * CS;       // [NCH][C*S]

    k_proj <<<LL / 16,          256, 0, stream>>>(x, Bk, Bb, Ck, Cb, Dk, Db, Bmat, Cmat, DTm);
    k_chunk<<<(NCH * CS) / 256, 256, 0, stream>>>(x, Al, Bmat, DTm, Aagg, Uagg);
    k_scan <<<CS / 256,         256, 0, stream>>>(Aagg, Uagg, Hpre);
    k_emit <<<(NCH * CS) / 256, 256, 0, stream>>>(x, Al, Bmat, Cmat, DTm, Hpre, y);
}

// Round 2
// 88.307 us; speedup vs baseline: 1.0185x; 1.0185x over previous
//
#include <hip/hip_runtime.h>
#include <math.h>

#define LL 4096
#define CC 128
#define SS 64
#define NCH 128
#define CLEN 32    // LL/NCH
#define CS 8192    // CC*SS

// ---------------- kernel 1: projections (B, Cm, dt) ----------------
__global__ __launch_bounds__(256) void k_proj(
    const float* __restrict__ x,
    const float* __restrict__ Bk, const float* __restrict__ Bb,
    const float* __restrict__ Ck, const float* __restrict__ Cb,
    const float* __restrict__ Dk, const float* __restrict__ Db,
    float* __restrict__ Bmat, float* __restrict__ Cmat, float* __restrict__ DTm)
{
    __shared__ float xs[CC][20];   // transposed x tile [k][row]; stride 20 (80B, 16B-aligned)
    const int r0 = blockIdx.x * 16;
    const int t = threadIdx.x;
    for (int i = t; i < 16 * CC; i += 256) {
        int r = i >> 7, k = i & 127;
        xs[k][r] = x[(r0 + r) * CC + k];
    }
    __syncthreads();
    const int col = t;             // 0..63 -> B, 64..127 -> Cm, 128..255 -> dt
    const float* W; int stride; float bias;
    if (col < 64)       { W = Bk + col;       stride = SS; bias = 1.0f + Bb[col]; }
    else if (col < 128) { W = Ck + (col-64);  stride = SS; bias = Cb[col-64]; }
    else                { W = Dk + (col-128); stride = CC; bias = Db[col-128] + 0.000244140625f; }
    float acc[16];
#pragma unroll
    for (int r = 0; r < 16; ++r) acc[r] = 0.0f;
    for (int k = 0; k < CC; ++k) {
        float w = W[k * stride];
#pragma unroll
        for (int r = 0; r < 16; ++r) acc[r] = fmaf(w, xs[k][r], acc[r]);
    }
    if (col < 64) {
#pragma unroll
        for (int r = 0; r < 16; ++r) Bmat[(r0 + r) * SS + col] = bias + acc[r];
    } else if (col < 128) {
#pragma unroll
        for (int r = 0; r < 16; ++r) Cmat[(r0 + r) * SS + (col - 64)] = bias + acc[r];
    } else {
#pragma unroll
        for (int r = 0; r < 16; ++r) {
            float z = bias + acc[r];
            float sp = fmaxf(z, 0.0f) + log1pf(__expf(-fabsf(z)));  // stable softplus
            DTm[(r0 + r) * CC + (col - 128)] = sp;
        }
    }
}

// ---------------- kernel 2: per-chunk aggregates (uc, sum dt) ----------------
__global__ __launch_bounds__(256) void k_chunk(
    const float* __restrict__ x, const float* __restrict__ A_log,
    const float* __restrict__ Bmat, const float* __restrict__ DTm,
    float* __restrict__ Uagg, float* __restrict__ sumdt)
{
    const int lane = threadIdx.x & 63;
    const int gw = blockIdx.x * 4 + (threadIdx.x >> 6);
    const int c  = __builtin_amdgcn_readfirstlane(gw & (CC - 1));
    const int ch = __builtin_amdgcn_readfirstlane(gw >> 7);
    const float A = -__expf(A_log[c * SS + lane]);
    const float invA = 1.0f / A;
    const int l0 = ch * CLEN;
    const float* dtp = DTm  + l0 * CC + c;   // wave-uniform -> s_load
    const float* xp  = x    + l0 * CC + c;   // wave-uniform -> s_load
    const float* Bp  = Bmat + l0 * SS + lane;
    float uc = 0.0f, sd = 0.0f;
#pragma unroll
    for (int i = 0; i < CLEN; ++i) {
        const float dtl = dtp[i * CC];
        const float xl  = xp[i * CC];
        const float Bl  = Bp[i * SS];
        const float At  = __expf(A * dtl);
        const float u   = (At - 1.0f) * invA * (Bl * xl);
        uc = fmaf(At, uc, u);
        sd += dtl;
    }
    Uagg[ch * CS + c * SS + lane] = uc;
    if (lane == 0) sumdt[ch * CC + c] = sd;
}

// ---------------- kernel 3: cross-chunk exclusive scan (in-place Uagg->Hpre) --
__global__ __launch_bounds__(256) void k_scan(
    const float* __restrict__ A_log, const float* __restrict__ sumdt,
    float* __restrict__ UH)
{
    const int j = blockIdx.x * 256 + threadIdx.x;   // (c,s) flat
    const int c = j >> 6;
    const float A = -__expf(A_log[j]);
    float h = 0.0f;
    for (int ch = 0; ch < NCH; ++ch) {
        const float a = __expf(A * sumdt[ch * CC + c]);
        const float u = UH[ch * CS + j];
        UH[ch * CS + j] = h;            // exclusive prefix (Hpre)
        h = fmaf(a, h, u);
    }
}

// ---------------- kernel 4: re-walk + batched transpose-reduce emit ----------
__global__ __launch_bounds__(256) void k_emit(
    const float* __restrict__ x, const float* __restrict__ A_log,
    const float* __restrict__ Bmat, const float* __restrict__ Cmat,
    const float* __restrict__ DTm, const float* __restrict__ Hpre,
    float* __restrict__ y)
{
    const int lane = threadIdx.x & 63;
    const int gw = blockIdx.x * 4 + (threadIdx.x >> 6);
    const int c  = __builtin_amdgcn_readfirstlane(gw & (CC - 1));
    const int ch = __builtin_amdgcn_readfirstlane(gw >> 7);
    const float A = -__expf(A_log[c * SS + lane]);
    const float invA = 1.0f / A;
    const int l0 = ch * CLEN;
    const float* dtp = DTm  + l0 * CC + c;   // wave-uniform -> s_load
    const float* xp  = x    + l0 * CC + c;
    const float* Bp  = Bmat + l0 * SS + lane;
    const float* Cp  = Cmat + l0 * SS + lane;
    float h = Hpre[ch * CS + c * SS + lane];
    float p[CLEN];
#pragma unroll
    for (int i = 0; i < CLEN; ++i) {
        const float dtl = dtp[i * CC];
        const float xl  = xp[i * CC];
        const float Bl  = Bp[i * SS];
        const float Cl  = Cp[i * SS];
        const float At  = __expf(A * dtl);
        const float u   = (At - 1.0f) * invA * (Bl * xl);
        h = fmaf(At, h, u);
        p[i] = Cl * h;
    }
    // batched 32-row x 64-lane transpose-reduce:
    // after stage k, p[i] holds row i*2^(k+1) + (lane & (2^(k+1)-1)),
    // summed over partner lanes in bits 0..k.
#pragma unroll
    for (int k = 0; k < 5; ++k) {
        const int d = 1 << k;
        const bool hi = (lane & d) != 0;
#pragma unroll
        for (int i = 0; i < (CLEN >> (k + 1)); ++i) {
            const float a = p[2 * i], b = p[2 * i + 1];
            const float send = hi ? a : b;
            const float t = __shfl_xor(send, d, 64);
            p[i] = (hi ? b : a) + t;
        }
    }
    // fold upper 32 lanes into lower: full sum over all 64 s
    const float t = __shfl_xor(p[0], 32, 64);
    const float yv = p[0] + t;
    if (lane < 32) y[(l0 + lane) * CC + c] = yv;
}

extern "C" void kernel_launch(void* const* d_in, const int* in_sizes, int n_in,
                              void* d_out, int out_size, void* d_ws, size_t ws_size,
                              hipStream_t stream)
{
    const float* x  = (const float*)d_in[0];
    const float* Al = (const float*)d_in[1];
    const float* Bk = (const float*)d_in[2];
    const float* Bb = (const float*)d_in[3];
    const float* Ck = (const float*)d_in[4];
    const float* Cb = (const float*)d_in[5];
    const float* Dk = (const float*)d_in[6];
    const float* Db = (const float*)d_in[7];
    float* y  = (float*)d_out;
    float* ws = (float*)d_ws;

    float* Bmat  = ws;                    // [L][S]      1 MB
    float* Cmat  = Bmat + LL * SS;        // [L][S]      1 MB
    float* DTm   = Cmat + LL * SS;        // [L][C]      2 MB
    float* UH    = DTm  + LL * CC;        // [NCH][C*S]  4 MB (Uagg, then Hpre in-place)
    float* sumdt = UH   + NCH * CS;       // [NCH][C]    64 KB

    k_proj <<<LL / 16,          256, 0, stream>>>(x, Bk, Bb, Ck, Cb, Dk, Db, Bmat, Cmat, DTm);
    k_chunk<<<(NCH * CS) / 256, 256, 0, stream>>>(x, Al, Bmat, DTm, UH, sumdt);
    k_scan <<<CS / 256,         256, 0, stream>>>(Al, sumdt, UH);
    k_emit <<<(NCH * CS) / 256, 256, 0, stream>>>(x, Al, Bmat, Cmat, DTm, UH, y);
}

// Round 3
// 71.322 us; speedup vs baseline: 1.2610x; 1.2381x over previous
//
#include <hip/hip_runtime.h>
#include <math.h>

#define LL 4096
#define CC 128
#define SS 64
#define NCH 128
#define CLEN 32    // LL/NCH
#define CS 8192    // CC*SS
#define GW 8       // chunks (waves) per k_chunk block
#define NG 16      // NCH/GW groups

// ---------------- kernel 1: projections (B, Cm, dt) ----------------
__global__ __launch_bounds__(256) void k_proj(
    const float* __restrict__ x,
    const float* __restrict__ Bk, const float* __restrict__ Bb,
    const float* __restrict__ Ck, const float* __restrict__ Cb,
    const float* __restrict__ Dk, const float* __restrict__ Db,
    float* __restrict__ Bmat, float* __restrict__ Cmat, float* __restrict__ DTm)
{
    __shared__ float xs[CC][20];   // transposed x tile [k][row]; 80B rows, 16B-aligned
    const int r0 = blockIdx.x * 16;
    const int t = threadIdx.x;
    for (int i = t; i < 16 * CC; i += 256) {
        int r = i >> 7, k = i & 127;
        xs[k][r] = x[(r0 + r) * CC + k];
    }
    __syncthreads();
    const int col = t;             // 0..63 -> B, 64..127 -> Cm, 128..255 -> dt
    const float* W; int stride; float bias;
    if (col < 64)       { W = Bk + col;       stride = SS; bias = 1.0f + Bb[col]; }
    else if (col < 128) { W = Ck + (col-64);  stride = SS; bias = Cb[col-64]; }
    else                { W = Dk + (col-128); stride = CC; bias = Db[col-128] + 0.000244140625f; }
    float4 acc[4];
#pragma unroll
    for (int q = 0; q < 4; ++q) acc[q] = make_float4(0.f, 0.f, 0.f, 0.f);
    for (int k = 0; k < CC; ++k) {
        const float w = W[k * stride];
        const float4* xr = (const float4*)&xs[k][0];   // 4 x ds_read_b128, broadcast
#pragma unroll
        for (int q = 0; q < 4; ++q) {
            const float4 v = xr[q];
            acc[q].x = fmaf(w, v.x, acc[q].x);
            acc[q].y = fmaf(w, v.y, acc[q].y);
            acc[q].z = fmaf(w, v.z, acc[q].z);
            acc[q].w = fmaf(w, v.w, acc[q].w);
        }
    }
    float accf[16];
#pragma unroll
    for (int q = 0; q < 4; ++q) {
        accf[4*q+0] = acc[q].x; accf[4*q+1] = acc[q].y;
        accf[4*q+2] = acc[q].z; accf[4*q+3] = acc[q].w;
    }
    if (col < 64) {
#pragma unroll
        for (int r = 0; r < 16; ++r) Bmat[(r0 + r) * SS + col] = bias + accf[r];
    } else if (col < 128) {
#pragma unroll
        for (int r = 0; r < 16; ++r) Cmat[(r0 + r) * SS + (col - 64)] = bias + accf[r];
    } else {
#pragma unroll
        for (int r = 0; r < 16; ++r) {
            float z = bias + accf[r];
            float sp = fmaxf(z, 0.0f) + log1pf(__expf(-fabsf(z)));  // stable softplus
            DTm[(r0 + r) * CC + (col - 128)] = sp;
        }
    }
}

// ------- kernel 2: per-chunk aggregates + in-block 8-wave scan -------
// block = 512 thr = 8 waves = 8 consecutive chunks of one c; lane = s.
__global__ __launch_bounds__(512) void k_chunk(
    const float* __restrict__ x, const float* __restrict__ A_log,
    const float* __restrict__ Bmat, const float* __restrict__ DTm,
    float* __restrict__ Ea, float* __restrict__ Eu,
    float* __restrict__ Ga, float* __restrict__ Gu)
{
    __shared__ float2 agg[GW][SS];
    const int lane = threadIdx.x & 63;
    const int w = threadIdx.x >> 6;        // 0..7 (chunk within group)
    const int c = blockIdx.x >> 4;         // SGPR
    const int g = blockIdx.x & (NG - 1);   // SGPR
    const int ch = g * GW + w;
    const float A = -__expf(A_log[c * SS + lane]);
    const float invA = 1.0f / A;
    const int l0 = ch * CLEN;
    const float* dtp = DTm  + l0 * CC + c;   // wave-uniform -> s_load
    const float* xp  = x    + l0 * CC + c;
    const float* Bp  = Bmat + l0 * SS + lane;
    float ap = 1.0f, uc = 0.0f;
#pragma unroll
    for (int i = 0; i < CLEN; ++i) {
        const float dtl = dtp[i * CC];
        const float xl  = xp[i * CC];
        const float Bl  = Bp[i * SS];
        const float At  = __expf(A * dtl);
        const float u   = (At - 1.0f) * invA * (Bl * xl);
        ap *= At;
        uc = fmaf(At, uc, u);
    }
    agg[w][lane] = make_float2(ap, uc);
    __syncthreads();
    // exclusive in-block prefix over waves 0..w-1 (compose order = time order)
    float ea = 1.0f, eu = 0.0f;
    for (int k = 0; k < w; ++k) {
        const float2 t = agg[k][lane];
        eu = fmaf(t.x, eu, t.y);
        ea *= t.x;
    }
    const int j = c * SS + lane;
    Ea[ch * CS + j] = ea;
    Eu[ch * CS + j] = eu;
    if (w == GW - 1) {                     // group aggregate (all 8 chunks)
        const float2 t = agg[GW - 1][lane];
        Gu[g * CS + j] = fmaf(t.x, eu, t.y);
        Ga[g * CS + j] = ea * t.x;
    }
}

// ---------------- kernel 3: cross-group exclusive scan (16 iters) ----------
__global__ __launch_bounds__(256) void k_mid(
    const float* __restrict__ Ga, const float* __restrict__ Gu,
    float* __restrict__ hG)
{
    const int j = blockIdx.x * 256 + threadIdx.x;   // (c,s) flat
    float h = 0.0f;
#pragma unroll
    for (int g = 0; g < NG; ++g) {
        hG[g * CS + j] = h;
        h = fmaf(Ga[g * CS + j], h, Gu[g * CS + j]);
    }
}

// ---------------- kernel 4: re-walk + batched transpose-reduce emit ----------
__global__ __launch_bounds__(256) void k_emit(
    const float* __restrict__ x, const float* __restrict__ A_log,
    const float* __restrict__ Bmat, const float* __restrict__ Cmat,
    const float* __restrict__ DTm,
    const float* __restrict__ Ea, const float* __restrict__ Eu,
    const float* __restrict__ hG,
    float* __restrict__ y)
{
    const int lane = threadIdx.x & 63;
    const int gw = blockIdx.x * 4 + (threadIdx.x >> 6);
    const int c  = __builtin_amdgcn_readfirstlane(gw & (CC - 1));
    const int ch = __builtin_amdgcn_readfirstlane(gw >> 7);
    const int g  = ch >> 3;
    const float A = -__expf(A_log[c * SS + lane]);
    const float invA = 1.0f / A;
    const int l0 = ch * CLEN;
    const int j = c * SS + lane;
    const float* dtp = DTm  + l0 * CC + c;   // wave-uniform -> s_load
    const float* xp  = x    + l0 * CC + c;
    const float* Bp  = Bmat + l0 * SS + lane;
    const float* Cp  = Cmat + l0 * SS + lane;
    float h = fmaf(Ea[ch * CS + j], hG[g * CS + j], Eu[ch * CS + j]);
    float p[CLEN];
#pragma unroll
    for (int i = 0; i < CLEN; ++i) {
        const float dtl = dtp[i * CC];
        const float xl  = xp[i * CC];
        const float Bl  = Bp[i * SS];
        const float Cl  = Cp[i * SS];
        const float At  = __expf(A * dtl);
        const float u   = (At - 1.0f) * invA * (Bl * xl);
        h = fmaf(At, h, u);
        p[i] = Cl * h;
    }
    // batched 32-row x 64-lane transpose-reduce (register-halving butterfly)
#pragma unroll
    for (int k = 0; k < 5; ++k) {
        const int d = 1 << k;
        const bool hi = (lane & d) != 0;
#pragma unroll
        for (int i = 0; i < (CLEN >> (k + 1)); ++i) {
            const float a = p[2 * i], b = p[2 * i + 1];
            const float send = hi ? a : b;
            const float t = __shfl_xor(send, d, 64);
            p[i] = (hi ? b : a) + t;
        }
    }
    const float t = __shfl_xor(p[0], 32, 64);
    const float yv = p[0] + t;
    if (lane < 32) y[(l0 + lane) * CC + c] = yv;
}

extern "C" void kernel_launch(void* const* d_in, const int* in_sizes, int n_in,
                              void* d_out, int out_size, void* d_ws, size_t ws_size,
                              hipStream_t stream)
{
    const float* x  = (const float*)d_in[0];
    const float* Al = (const float*)d_in[1];
    const float* Bk = (const float*)d_in[2];
    const float* Bb = (const float*)d_in[3];
    const float* Ck = (const float*)d_in[4];
    const float* Cb = (const float*)d_in[5];
    const float* Dk = (const float*)d_in[6];
    const float* Db = (const float*)d_in[7];
    float* y  = (float*)d_out;
    float* ws = (float*)d_ws;

    float* Bmat = ws;                    // [L][S]       1 MB
    float* Cmat = Bmat + LL * SS;        // [L][S]       1 MB
    float* DTm  = Cmat + LL * SS;        // [L][C]       2 MB
    float* Ea   = DTm  + LL * CC;        // [NCH][CS]    4 MB
    float* Eu   = Ea   + NCH * CS;       // [NCH][CS]    4 MB
    float* Ga   = Eu   + NCH * CS;       // [NG][CS]     0.5 MB
    float* Gu   = Ga   + NG * CS;        // [NG][CS]     0.5 MB
    float* hG   = Gu   + NG * CS;        // [NG][CS]     0.5 MB

    k_proj <<<LL / 16,           256, 0, stream>>>(x, Bk, Bb, Ck, Cb, Dk, Db, Bmat, Cmat, DTm);
    k_chunk<<<CC * NG,           512, 0, stream>>>(x, Al, Bmat, DTm, Ea, Eu, Ga, Gu);
    k_mid  <<<CS / 256,          256, 0, stream>>>(Ga, Gu, hG);
    k_emit <<<(NCH * CS) / 256,  256, 0, stream>>>(x, Al, Bmat, Cmat, DTm, Ea, Eu, hG, y);
}

// Round 4
// 58.299 us; speedup vs baseline: 1.5427x; 1.2234x over previous
//
#include <hip/hip_runtime.h>
#include <math.h>

#define LL 4096
#define CC 128
#define SS 64
#define NCH 128
#define CLEN 32    // LL/NCH
#define CS 8192    // CC*SS
#define GW 8       // chunks (waves) per k_chunk block
#define NG 16      // NCH/GW groups

// ---------------- kernel 1: projections (B, Cm, dtT) + xT ----------------
// 256 blocks x 256 thr; block = 16 rows x 256 cols; thread tile = 4x4.
__global__ __launch_bounds__(256) void k_proj(
    const float* __restrict__ x,
    const float* __restrict__ Bk, const float* __restrict__ Bb,
    const float* __restrict__ Ck, const float* __restrict__ Cb,
    const float* __restrict__ Dk, const float* __restrict__ Db,
    float* __restrict__ Bmat, float* __restrict__ Cmat,
    float* __restrict__ DTmT, float* __restrict__ xT)
{
    __shared__ float xs[CC][20];   // transposed x tile [k][row]; 80B rows, 16B-aligned
    const int r0 = blockIdx.x * 16;
    const int t = threadIdx.x;
    {
        const int r = t >> 4, k8 = (t & 15) * 8;
        const float4 v0 = *(const float4*)&x[(r0 + r) * CC + k8];
        const float4 v1 = *(const float4*)&x[(r0 + r) * CC + k8 + 4];
        xs[k8+0][r] = v0.x; xs[k8+1][r] = v0.y; xs[k8+2][r] = v0.z; xs[k8+3][r] = v0.w;
        xs[k8+4][r] = v1.x; xs[k8+5][r] = v1.y; xs[k8+6][r] = v1.z; xs[k8+7][r] = v1.w;
    }
    __syncthreads();
    {   // emit x transposed [C][L] (free: tile already transposed in LDS)
        const int k = t >> 1, half = (t & 1) * 8;
        const float4 a = *(const float4*)&xs[k][half];
        const float4 b = *(const float4*)&xs[k][half + 4];
        *(float4*)&xT[k * LL + r0 + half]     = a;
        *(float4*)&xT[k * LL + r0 + half + 4] = b;
    }
    const int tc = t & 63, tr = t >> 6;
    const float* Wb; int wstride, wo;
    if (tc < 16)      { Wb = Bk; wstride = SS; wo = 4 * tc; }
    else if (tc < 32) { Wb = Ck; wstride = SS; wo = 4 * tc - 64; }
    else              { Wb = Dk; wstride = CC; wo = 4 * tc - 128; }
    float acc[4][4];
#pragma unroll
    for (int r = 0; r < 4; ++r)
#pragma unroll
        for (int j = 0; j < 4; ++j) acc[r][j] = 0.0f;
    for (int k = 0; k < CC; ++k) {
        const float4 wq = *(const float4*)(Wb + k * wstride + wo);  // L1/L2-cached
        const float4 xq = *(const float4*)&xs[k][4 * tr];           // 1 b128, wave-broadcast
        const float wv[4] = {wq.x, wq.y, wq.z, wq.w};
        const float xv[4] = {xq.x, xq.y, xq.z, xq.w};
#pragma unroll
        for (int r = 0; r < 4; ++r)
#pragma unroll
            for (int j = 0; j < 4; ++j) acc[r][j] = fmaf(xv[r], wv[j], acc[r][j]);
    }
    const int rb = r0 + 4 * tr;
    if (tc < 32) {
        const float* bb = (tc < 16) ? Bb : Cb;
        const float add = (tc < 16) ? 1.0f : 0.0f;
        float bias[4];
#pragma unroll
        for (int j = 0; j < 4; ++j) bias[j] = add + bb[wo + j];
        float* dst = (tc < 16) ? Bmat : Cmat;
#pragma unroll
        for (int r = 0; r < 4; ++r) {
            const float4 o = make_float4(acc[r][0] + bias[0], acc[r][1] + bias[1],
                                         acc[r][2] + bias[2], acc[r][3] + bias[3]);
            *(float4*)&dst[(rb + r) * SS + wo] = o;
        }
    } else {
#pragma unroll
        for (int j = 0; j < 4; ++j) {
            const float bj = Db[wo + j] + 0.000244140625f;
            float sp[4];
#pragma unroll
            for (int r = 0; r < 4; ++r) {
                const float z = acc[r][j] + bj;
                sp[r] = fmaxf(z, 0.0f) + log1pf(__expf(-fabsf(z)));  // stable softplus
            }
            *(float4*)&DTmT[(wo + j) * LL + rb] = make_float4(sp[0], sp[1], sp[2], sp[3]);
        }
    }
}

// ------- kernel 2: per-chunk aggregates + in-block 8-wave scan -------
// block = 512 thr = 8 waves = 8 consecutive chunks of one c; lane = s.
__global__ __launch_bounds__(512) void k_chunk(
    const float* __restrict__ xT, const float* __restrict__ A_log,
    const float* __restrict__ Bmat, const float* __restrict__ DTmT,
    float* __restrict__ Ea, float* __restrict__ Eu,
    float* __restrict__ Ga, float* __restrict__ Gu)
{
    __shared__ float2 agg[GW][SS];
    const int lane = threadIdx.x & 63;
    const int w = threadIdx.x >> 6;        // 0..7 (chunk within group)
    const int c = blockIdx.x >> 4;         // SGPR
    const int g = blockIdx.x & (NG - 1);   // SGPR
    const int ch = __builtin_amdgcn_readfirstlane(g * GW + w);
    const float A = -__expf(A_log[c * SS + lane]);
    const float invA = 1.0f / A;
    const int l0 = ch * CLEN;
    const float* dtp = DTmT + c * LL + l0;   // uniform + contiguous -> s_load_dwordx16
    const float* xp  = xT   + c * LL + l0;   // uniform + contiguous -> s_load_dwordx16
    const float* Bp  = Bmat + l0 * SS + lane;
    float ap = 1.0f, uc = 0.0f;
#pragma unroll
    for (int i = 0; i < CLEN; ++i) {
        const float dtl = dtp[i];
        const float xl  = xp[i];
        const float Bl  = Bp[i * SS];
        const float At  = __expf(A * dtl);
        const float u   = (At - 1.0f) * invA * (Bl * xl);
        ap *= At;
        uc = fmaf(At, uc, u);
    }
    agg[w][lane] = make_float2(ap, uc);
    __syncthreads();
    // exclusive in-block prefix over waves 0..w-1 (compose order = time order)
    float ea = 1.0f, eu = 0.0f;
    for (int k = 0; k < w; ++k) {
        const float2 tt = agg[k][lane];
        eu = fmaf(tt.x, eu, tt.y);
        ea *= tt.x;
    }
    const int j = c * SS + lane;
    Ea[ch * CS + j] = ea;
    Eu[ch * CS + j] = eu;
    if (w == GW - 1) {                     // group aggregate (all 8 chunks)
        const float2 tt = agg[GW - 1][lane];
        Gu[g * CS + j] = fmaf(tt.x, eu, tt.y);
        Ga[g * CS + j] = ea * tt.x;
    }
}

// ---------------- kernel 3: cross-group exclusive scan (16 iters) ----------
__global__ __launch_bounds__(256) void k_mid(
    const float* __restrict__ Ga, const float* __restrict__ Gu,
    float* __restrict__ hG)
{
    const int j = blockIdx.x * 256 + threadIdx.x;   // (c,s) flat
    float h = 0.0f;
#pragma unroll
    for (int g = 0; g < NG; ++g) {
        hG[g * CS + j] = h;
        h = fmaf(Ga[g * CS + j], h, Gu[g * CS + j]);
    }
}

// ---------------- kernel 4: re-walk + batched transpose-reduce emit ----------
__global__ __launch_bounds__(256) void k_emit(
    const float* __restrict__ xT, const float* __restrict__ A_log,
    const float* __restrict__ Bmat, const float* __restrict__ Cmat,
    const float* __restrict__ DTmT,
    const float* __restrict__ Ea, const float* __restrict__ Eu,
    const float* __restrict__ hG,
    float* __restrict__ y)
{
    const int lane = threadIdx.x & 63;
    const int gw = blockIdx.x * 4 + (threadIdx.x >> 6);
    const int c  = __builtin_amdgcn_readfirstlane(gw & (CC - 1));
    const int ch = __builtin_amdgcn_readfirstlane(gw >> 7);
    const int g  = ch >> 3;
    const float A = -__expf(A_log[c * SS + lane]);
    const float invA = 1.0f / A;
    const int l0 = ch * CLEN;
    const int j = c * SS + lane;
    const float* dtp = DTmT + c * LL + l0;   // -> s_load_dwordx16
    const float* xp  = xT   + c * LL + l0;   // -> s_load_dwordx16
    const float* Bp  = Bmat + l0 * SS + lane;
    const float* Cp  = Cmat + l0 * SS + lane;
    float h = fmaf(Ea[ch * CS + j], hG[g * CS + j], Eu[ch * CS + j]);
    float p[CLEN];
#pragma unroll
    for (int i = 0; i < CLEN; ++i) {
        const float dtl = dtp[i];
        const float xl  = xp[i];
        const float Bl  = Bp[i * SS];
        const float Cl  = Cp[i * SS];
        const float At  = __expf(A * dtl);
        const float u   = (At - 1.0f) * invA * (Bl * xl);
        h = fmaf(At, h, u);
        p[i] = Cl * h;
    }
    // batched 32-row x 64-lane transpose-reduce (register-halving butterfly)
#pragma unroll
    for (int k = 0; k < 5; ++k) {
        const int d = 1 << k;
        const bool hi = (lane & d) != 0;
#pragma unroll
        for (int i = 0; i < (CLEN >> (k + 1)); ++i) {
            const float a = p[2 * i], b = p[2 * i + 1];
            const float send = hi ? a : b;
            const float t = __shfl_xor(send, d, 64);
            p[i] = (hi ? b : a) + t;
        }
    }
    const float t = __shfl_xor(p[0], 32, 64);
    const float yv = p[0] + t;
    if (lane < 32) y[(l0 + lane) * CC + c] = yv;
}

extern "C" void kernel_launch(void* const* d_in, const int* in_sizes, int n_in,
                              void* d_out, int out_size, void* d_ws, size_t ws_size,
                              hipStream_t stream)
{
    const float* x  = (const float*)d_in[0];
    const float* Al = (const float*)d_in[1];
    const float* Bk = (const float*)d_in[2];
    const float* Bb = (const float*)d_in[3];
    const float* Ck = (const float*)d_in[4];
    const float* Cb = (const float*)d_in[5];
    const float* Dk = (const float*)d_in[6];
    const float* Db = (const float*)d_in[7];
    float* y  = (float*)d_out;
    float* ws = (float*)d_ws;

    float* Bmat = ws;                    // [L][S]       1 MB
    float* Cmat = Bmat + LL * SS;        // [L][S]       1 MB
    float* DTmT = Cmat + LL * SS;        // [C][L]       2 MB (transposed)
    float* xT   = DTmT + CC * LL;        // [C][L]       2 MB (transposed)
    float* Ea   = xT   + CC * LL;        // [NCH][CS]    4 MB
    float* Eu   = Ea   + NCH * CS;       // [NCH][CS]    4 MB
    float* Ga   = Eu   + NCH * CS;       // [NG][CS]     0.5 MB
    float* Gu   = Ga   + NG * CS;        // [NG][CS]     0.5 MB
    float* hG   = Gu   + NG * CS;        // [NG][CS]     0.5 MB

    k_proj <<<LL / 16,           256, 0, stream>>>(x, Bk, Bb, Ck, Cb, Dk, Db, Bmat, Cmat, DTmT, xT);
    k_chunk<<<CC * NG,           512, 0, stream>>>(xT, Al, Bmat, DTmT, Ea, Eu, Ga, Gu);
    k_mid  <<<CS / 256,          256, 0, stream>>>(Ga, Gu, hG);
    k_emit <<<(NCH * CS) / 256,  256, 0, stream>>>(xT, Al, Bmat, Cmat, DTmT, Ea, Eu, hG, y);
}